// Round 1
// baseline (229.020 us; speedup 1.0000x reference)
//
#include <hip/hip_runtime.h>
#include <hip/hip_bf16.h>

// Problem constants (fixed by setup_inputs):
//   bs=8, nq=1500, C=2  -> NI = 12000 rows
//   total_tgt = 4800    -> NJ = 4800 cols
// Output: [NI][NJ] f32 = 230.4 MB  -> write-BW bound.
//
// C[i,j] = softplus(x0)+softplus(x1) - t0*x0 - t1*x1 + 5*(|px-tx|+|py-ty|)
// (uses log_sigmoid(x) - log_sigmoid(-x) = x; the mean-over-2-classes *2
//  cancels COST_CLASS=2)

#define NI 12000
#define NJ 4800
#define NJF (NJ / 4)      // 1200 float4 per row
#define ROWS 4            // rows per thread in main kernel

// ---- precompute: per-row quad (base,-x0,-x1,px) + py, per-target (t0,t1,tx,ty)
__global__ __launch_bounds__(256) void precompute_kernel(
    const float* __restrict__ pred_logits,   // [NI][2]
    const float* __restrict__ pred_points,   // [NI][2]
    const float* __restrict__ tgt_labels,    // [NJ][2]
    const float* __restrict__ tgt_points,    // [NJ][2]
    float4* __restrict__ wqa,                // [NI]
    float* __restrict__ wpy,                 // [NI]
    float4* __restrict__ wtgt)               // [NJ]
{
    int tid = blockIdx.x * blockDim.x + threadIdx.x;
    if (tid < NI) {
        float x0 = pred_logits[tid * 2 + 0];
        float x1 = pred_logits[tid * 2 + 1];
        // stable softplus(x) = max(x,0) + log1p(exp(-|x|))
        float sp0 = fmaxf(x0, 0.0f) + log1pf(expf(-fabsf(x0)));
        float sp1 = fmaxf(x1, 0.0f) + log1pf(expf(-fabsf(x1)));
        float4 q;
        q.x = sp0 + sp1;   // base
        q.y = -x0;         // coeff for t0
        q.z = -x1;         // coeff for t1
        q.w = pred_points[tid * 2 + 0];  // px
        wqa[tid] = q;
        wpy[tid] = pred_points[tid * 2 + 1];  // py
    } else if (tid < NI + NJ) {
        int j = tid - NI;
        float4 t;
        t.x = tgt_labels[j * 2 + 0];
        t.y = tgt_labels[j * 2 + 1];
        t.z = tgt_points[j * 2 + 0];
        t.w = tgt_points[j * 2 + 1];
        wtgt[j] = t;
    }
}

// ---- main: each thread -> 4 output cols (one float4) x ROWS rows.
// Reads are L2-resident (~317 KB total working set); stores are the
// only HBM traffic (coalesced float4, wave-wide 1 KiB per store inst).
__global__ __launch_bounds__(256) void cmat_kernel(
    const float4* __restrict__ wqa,
    const float* __restrict__ wpy,
    const float4* __restrict__ wtgt,
    float4* __restrict__ out)                // [NI][NJF]
{
    int jf = blockIdx.x * blockDim.x + threadIdx.x;   // float4-column index
    if (jf >= NJF) return;
    int i0 = blockIdx.y * ROWS;

    float4 qa[ROWS];
    float  py[ROWS];
#pragma unroll
    for (int r = 0; r < ROWS; ++r) {
        qa[r] = wqa[i0 + r];     // broadcast within the row-group (L1 hit)
        py[r] = wpy[i0 + r];
    }

    float4 acc[ROWS];
#pragma unroll
    for (int k = 0; k < 4; ++k) {
        float4 t = wtgt[jf * 4 + k];   // 64 B contiguous per thread, coalesced
#pragma unroll
        for (int r = 0; r < ROWS; ++r) {
            float cc = qa[r].x + qa[r].y * t.x + qa[r].z * t.y;
            float cp = fabsf(qa[r].w - t.z) + fabsf(py[r] - t.w);
            float v  = fmaf(5.0f, cp, cc);
            (&acc[r].x)[k] = v;        // k is compile-time after unroll
        }
    }

#pragma unroll
    for (int r = 0; r < ROWS; ++r) {
        out[(i0 + r) * NJF + jf] = acc[r];
    }
}

extern "C" void kernel_launch(void* const* d_in, const int* in_sizes, int n_in,
                              void* d_out, int out_size, void* d_ws, size_t ws_size,
                              hipStream_t stream) {
    const float* pred_logits = (const float*)d_in[0];  // 24000
    const float* pred_points = (const float*)d_in[1];  // 24000
    const float* tgt_labels  = (const float*)d_in[2];  // 9600
    const float* tgt_points  = (const float*)d_in[3];  // 9600
    float* out = (float*)d_out;                        // 57,600,000

    // ws layout: wqa [NI] float4 | wpy [NI] float | wtgt [NJ] float4
    char* ws = (char*)d_ws;
    float4* wqa  = (float4*)ws;                         // 192,000 B
    float*  wpy  = (float*)(ws + NI * sizeof(float4));  //  48,000 B
    float4* wtgt = (float4*)(ws + NI * sizeof(float4) + NI * sizeof(float));
    // total ws use: 316,800 B

    dim3 block(256);
    dim3 grid_pre((NI + NJ + 255) / 256);
    precompute_kernel<<<grid_pre, block, 0, stream>>>(
        pred_logits, pred_points, tgt_labels, tgt_points, wqa, wpy, wtgt);

    dim3 grid_main((NJF + 255) / 256, NI / ROWS);   // (5, 3000)
    cmat_kernel<<<grid_main, block, 0, stream>>>(wqa, wpy, wtgt, (float4*)out);
}